// Round 1
// baseline (1066.594 us; speedup 1.0000x reference)
//
#include <hip/hip_runtime.h>
#include <math.h>

#define NN 20000      // nodes
#define NE 320000     // edges (without self loops)
#define NT 340000     // edges + self loops
#define NG 64         // graphs

// ---------- helpers ----------
__device__ __forceinline__ unsigned f2key(float f) {
    unsigned u = __float_as_uint(f);
    return (u & 0x80000000u) ? ~u : (u | 0x80000000u);   // monotone map for atomicMax
}
__device__ __forceinline__ float key2f(unsigned k) {
    unsigned u = (k & 0x80000000u) ? (k & 0x7FFFFFFFu) : ~k;
    return __uint_as_float(u);
}
__device__ __forceinline__ float lrelu(float v) { return v > 0.f ? v : 0.2f * v; }
__device__ __forceinline__ float elu1(float v)  { return v > 0.f ? v : (expf(v) - 1.f); }

__device__ __forceinline__ int esrc(const int* ei, int e) { return e < NE ? ei[e] : (e - NE); }
__device__ __forceinline__ int edst(const int* ei, int e) { return e < NE ? ei[NE + e] : (e - NE); }

// ---------- layer 1 ----------
// h1[n][64] = x[n][3] @ W1[3][64]; al_s1/al_d1[n][8] head-wise dot with a_src1/a_dst1
__global__ void k1_h1(const float* __restrict__ x, const float* __restrict__ W1,
                      const float* __restrict__ as1, const float* __restrict__ ad1,
                      float* __restrict__ h1, float* __restrict__ al_s, float* __restrict__ al_d) {
    int n = blockIdx.x;
    int j = threadIdx.x;  // 0..63
    float x0 = x[n * 3 + 0], x1 = x[n * 3 + 1], x2 = x[n * 3 + 2];
    float v = fmaf(x0, W1[j], fmaf(x1, W1[64 + j], x2 * W1[128 + j]));
    h1[n * 64 + j] = v;
    float ps = v * as1[j];
    float pd = v * ad1[j];
    // reduce over the 8 channels of each head (8 consecutive lanes)
    for (int o = 4; o >= 1; o >>= 1) {
        ps += __shfl_xor(ps, o, 8);
        pd += __shfl_xor(pd, o, 8);
    }
    if ((j & 7) == 0) {
        al_s[n * 8 + (j >> 3)] = ps;
        al_d[n * 8 + (j >> 3)] = pd;
    }
}

// per (edge, head): e = leaky_relu(al_s[src]+al_d[dst]); segment max into m1 (uint keys)
__global__ void k2_logit1(const int* __restrict__ ei, const float* __restrict__ al_s,
                          const float* __restrict__ al_d, float* __restrict__ e1,
                          unsigned* __restrict__ m1) {
    int t = blockIdx.x * blockDim.x + threadIdx.x;
    if (t >= NT * 8) return;
    int e = t >> 3, h = t & 7;
    int s = esrc(ei, e), d = edst(ei, e);
    float v = lrelu(al_s[s * 8 + h] + al_d[d * 8 + h]);
    e1[t] = v;
    atomicMax(&m1[d * 8 + h], f2key(v));
}

// per (edge, head): ex = exp(e - m[dst]); denom[dst] += ex
__global__ void k3_exp1(const int* __restrict__ ei, const unsigned* __restrict__ m1,
                        float* __restrict__ e1, float* __restrict__ denom1) {
    int t = blockIdx.x * blockDim.x + threadIdx.x;
    if (t >= NT * 8) return;
    int e = t >> 3, h = t & 7;
    int d = edst(ei, e);
    float ex = expf(e1[t] - key2f(m1[d * 8 + h]));
    e1[t] = ex;
    atomicAdd(&denom1[d * 8 + h], ex);
}

// per (edge, ch64): acc1[dst][j] += ex1[e][h] * h1[src][j]   (normalize later)
__global__ void k4_agg1(const int* __restrict__ ei, const float* __restrict__ ex1,
                        const float* __restrict__ h1, float* __restrict__ acc1) {
    int t = blockIdx.x * blockDim.x + threadIdx.x;
    if (t >= NT * 64) return;
    int e = t >> 6, j = t & 63;
    int s = esrc(ei, e), d = edst(ei, e);
    int h = j >> 3;
    atomicAdd(&acc1[d * 64 + j], ex1[e * 8 + h] * h1[s * 64 + j]);
}

// o1 = elu(acc1/denom1 + b1)  (in place on acc1)
__global__ void k5a_o1(float* __restrict__ acc1, const float* __restrict__ denom1,
                       const float* __restrict__ b1) {
    int t = blockIdx.x * blockDim.x + threadIdx.x;
    if (t >= NN * 64) return;
    int n = t >> 6, j = t & 63;
    float v = acc1[t] / denom1[n * 8 + (j >> 3)] + b1[j];
    acc1[t] = elu1(v);
}

// h2[n][512] = o1[n][64] @ W2[64][512]; al_s2/al_d2[n] = dot(h2[n], a2)
__global__ void k5b_h2(const float* __restrict__ o1, const float* __restrict__ W2,
                       const float* __restrict__ as2, const float* __restrict__ ad2,
                       float* __restrict__ h2, float* __restrict__ al_s2,
                       float* __restrict__ al_d2) {
    __shared__ float sO[64];
    __shared__ float rs[8], rd[8];
    int n = blockIdx.x, j = threadIdx.x;  // 512 threads
    if (j < 64) sO[j] = o1[n * 64 + j];
    __syncthreads();
    float v = 0.f;
#pragma unroll
    for (int k = 0; k < 64; ++k) v = fmaf(sO[k], W2[k * 512 + j], v);
    h2[n * 512 + j] = v;
    float ps = v * as2[j];
    float pd = v * ad2[j];
    for (int o = 32; o >= 1; o >>= 1) {
        ps += __shfl_xor(ps, o, 64);
        pd += __shfl_xor(pd, o, 64);
    }
    int w = j >> 6;
    if ((j & 63) == 0) { rs[w] = ps; rd[w] = pd; }
    __syncthreads();
    if (j == 0) {
        float s = 0.f, d = 0.f;
        for (int i = 0; i < 8; ++i) { s += rs[i]; d += rd[i]; }
        al_s2[n] = s;
        al_d2[n] = d;
    }
}

// ---------- layer 2 ----------
__global__ void k6_logit2(const int* __restrict__ ei, const float* __restrict__ al_s2,
                          const float* __restrict__ al_d2, float* __restrict__ e2,
                          unsigned* __restrict__ m2) {
    int t = blockIdx.x * blockDim.x + threadIdx.x;
    if (t >= NT) return;
    int s = esrc(ei, t), d = edst(ei, t);
    float v = lrelu(al_s2[s] + al_d2[d]);
    e2[t] = v;
    atomicMax(&m2[d], f2key(v));
}

__global__ void k7_exp2(const int* __restrict__ ei, const unsigned* __restrict__ m2,
                        float* __restrict__ e2, float* __restrict__ denom2) {
    int t = blockIdx.x * blockDim.x + threadIdx.x;
    if (t >= NT) return;
    int d = edst(ei, t);
    float ex = expf(e2[t] - key2f(m2[d]));
    e2[t] = ex;
    atomicAdd(&denom2[d], ex);
}

// per (edge, ch512): out2[dst][j] += ex2[e] * h2[src][j]
__global__ void k8_agg2(const int* __restrict__ ei, const float* __restrict__ ex2,
                        const float* __restrict__ h2, float* __restrict__ out2) {
    long long t = (long long)blockIdx.x * blockDim.x + threadIdx.x;
    if (t >= (long long)NT * 512) return;
    int e = (int)(t >> 9), j = (int)(t & 511);
    int s = esrc(ei, e), d = edst(ei, e);
    atomicAdd(&out2[d * 512 + j], ex2[e] * h2[s * 512 + j]);
}

// ---------- pooling + output ----------
__global__ void k9_cnt(const int* __restrict__ batch, float* __restrict__ cnt) {
    int t = blockIdx.x * blockDim.x + threadIdx.x;
    if (t >= NN) return;
    atomicAdd(&cnt[batch[t]], 1.0f);
}

// o2 = elu(out2/denom2 + b2); sums[batch[n]] += o2
__global__ void k9_pool(const float* __restrict__ out2, const float* __restrict__ denom2,
                        const float* __restrict__ b2, const int* __restrict__ batch,
                        float* __restrict__ sums) {
    int t = blockIdx.x * blockDim.x + threadIdx.x;
    if (t >= NN * 512) return;
    int n = t >> 9, j = t & 511;
    float v = elu1(out2[t] / denom2[n] + b2[j]);
    atomicAdd(&sums[batch[n] * 512 + j], v);
}

// out[g][j] = (sums[g]/max(cnt,1)) @ Wo + bo
__global__ void k10_final(const float* __restrict__ sums, const float* __restrict__ cnt,
                          const float* __restrict__ Wo, const float* __restrict__ bo,
                          float* __restrict__ out) {
    __shared__ float sp[512];
    int g = blockIdx.x, j = threadIdx.x;
    float c = cnt[g];
    c = c > 0.f ? c : 1.f;
    sp[j] = sums[g * 512 + j] / c;
    __syncthreads();
    float v = bo[j];
    for (int k = 0; k < 512; ++k) v = fmaf(sp[k], Wo[k * 512 + j], v);
    out[g * 512 + j] = v;
}

extern "C" void kernel_launch(void* const* d_in, const int* in_sizes, int n_in,
                              void* d_out, int out_size, void* d_ws, size_t ws_size,
                              hipStream_t stream) {
    const float* x     = (const float*)d_in[0];
    const int*   ei    = (const int*)d_in[1];    // [2, NE]
    const int*   batch = (const int*)d_in[2];    // [NN]
    const float* W1    = (const float*)d_in[3];
    const float* as1   = (const float*)d_in[4];
    const float* ad1   = (const float*)d_in[5];
    const float* b1    = (const float*)d_in[6];
    const float* W2    = (const float*)d_in[7];
    const float* as2   = (const float*)d_in[8];
    const float* ad2   = (const float*)d_in[9];
    const float* b2    = (const float*)d_in[10];
    const float* Wo    = (const float*)d_in[11];
    const float* bo    = (const float*)d_in[12];
    float* out = (float*)d_out;

    // ---- workspace arena (floats) ----
    float* w = (float*)d_ws;
    float*    h1     = w + 0;          // 1,280,000
    float*    e1     = w + 1280000;    // 2,720,000 (logits, then exp, per edge*8)
    float*    al_s1  = w + 4000000;    // 160,000
    float*    al_d1  = w + 4160000;    // 160,000
    float*    h2     = w + 4320000;    // 10,240,000
    float*    al_s2  = w + 14560000;   // 20,000
    float*    al_d2  = w + 14580000;   // 20,000
    float*    e2     = w + 14600000;   // 340,000
    // ---- zero-initialized region (single contiguous memset) ----
    unsigned* m1     = (unsigned*)(w + 14940000);  // 160,000
    float*    denom1 = w + 15100000;   // 160,000
    float*    acc1   = w + 15260000;   // 1,280,000 (becomes o1 in place)
    unsigned* m2     = (unsigned*)(w + 16540000);  // 20,000
    float*    denom2 = w + 16560000;   // 20,000
    float*    out2   = w + 16580000;   // 10,240,000
    float*    sums   = w + 26820000;   // 32,768
    float*    cnt    = w + 26852768;   // 64
    // total: 26,852,832 floats = ~102.4 MiB

    hipMemsetAsync(w + 14940000, 0, (size_t)(26852832 - 14940000) * sizeof(float), stream);

    k1_h1<<<NN, 64, 0, stream>>>(x, W1, as1, ad1, h1, al_s1, al_d1);
    k2_logit1<<<(NT * 8 + 255) / 256, 256, 0, stream>>>(ei, al_s1, al_d1, e1, m1);
    k3_exp1<<<(NT * 8 + 255) / 256, 256, 0, stream>>>(ei, m1, e1, denom1);
    k4_agg1<<<(NT * 64 + 255) / 256, 256, 0, stream>>>(ei, e1, h1, acc1);
    k5a_o1<<<(NN * 64 + 255) / 256, 256, 0, stream>>>(acc1, denom1, b1);
    k5b_h2<<<NN, 512, 0, stream>>>(acc1, W2, as2, ad2, h2, al_s2, al_d2);
    k6_logit2<<<(NT + 255) / 256, 256, 0, stream>>>(ei, al_s2, al_d2, e2, m2);
    k7_exp2<<<(NT + 255) / 256, 256, 0, stream>>>(ei, m2, e2, denom2);
    {
        long long tot = (long long)NT * 512;
        int blocks = (int)((tot + 255) / 256);
        k8_agg2<<<blocks, 256, 0, stream>>>(ei, e2, h2, out2);
    }
    k9_cnt<<<(NN + 255) / 256, 256, 0, stream>>>(batch, cnt);
    k9_pool<<<(NN * 512 + 255) / 256, 256, 0, stream>>>(out2, denom2, b2, batch, sums);
    k10_final<<<NG, 512, 0, stream>>>(sums, cnt, Wo, bo, out);
}

// Round 2
// 500.490 us; speedup vs baseline: 2.1311x; 2.1311x over previous
//
#include <hip/hip_runtime.h>
#include <math.h>

#define NN 20000      // nodes
#define NE 320000     // edges (without self loops)
#define NT 340000     // edges + self loops
#define NG 64         // graphs

__device__ __forceinline__ float lrelu(float v) { return v > 0.f ? v : 0.2f * v; }
__device__ __forceinline__ float elu1(float v)  { return v > 0.f ? v : (expf(v) - 1.f); }

__device__ __forceinline__ int esrc(const int* ei, int e) { return e < NE ? ei[e] : (e - NE); }
__device__ __forceinline__ int edst(const int* ei, int e) { return e < NE ? ei[NE + e] : (e - NE); }

// ---------- CSR build (by dst) ----------
__global__ void k_hist(const int* __restrict__ ei, int* __restrict__ deg) {
    int t = blockIdx.x * blockDim.x + threadIdx.x;
    if (t >= NT) return;
    atomicAdd(&deg[edst(ei, t)], 1);
}

// single-block exclusive scan of deg[20000] -> rowstart[20001], cursor copy
__global__ void k_scan(const int* __restrict__ deg, int* __restrict__ rowstart,
                       int* __restrict__ cursor) {
    __shared__ int part[1024];
    int t = threadIdx.x;
    int base = t * 20;
    int local[20];
    int s = 0;
    if (base < NN) {
#pragma unroll
        for (int i = 0; i < 20; ++i) { local[i] = deg[base + i]; s += local[i]; }
    }
    part[t] = s;
    __syncthreads();
    for (int o = 1; o < 1024; o <<= 1) {
        int v = (t >= o) ? part[t - o] : 0;
        __syncthreads();
        part[t] += v;
        __syncthreads();
    }
    if (base < NN) {
        int run = (t == 0) ? 0 : part[t - 1];
#pragma unroll
        for (int i = 0; i < 20; ++i) {
            rowstart[base + i] = run;
            cursor[base + i] = run;
            run += local[i];
        }
    }
    if (t == 1023) rowstart[NN] = part[1023];
}

__global__ void k_scatter(const int* __restrict__ ei, int* __restrict__ cursor,
                          int* __restrict__ csr_src) {
    int t = blockIdx.x * blockDim.x + threadIdx.x;
    if (t >= NT) return;
    int d = edst(ei, t), s = esrc(ei, t);
    int pos = atomicAdd(&cursor[d], 1);
    csr_src[pos] = s;
}

// ---------- layer 1 ----------
// h1[n][64] = x[n][3] @ W1[3][64]; al_s1/al_d1[n][8] head-wise dot with a_src1/a_dst1
__global__ void k1_h1(const float* __restrict__ x, const float* __restrict__ W1,
                      const float* __restrict__ as1, const float* __restrict__ ad1,
                      float* __restrict__ h1, float* __restrict__ al_s, float* __restrict__ al_d) {
    int n = blockIdx.x;
    int j = threadIdx.x;  // 0..63
    float x0 = x[n * 3 + 0], x1 = x[n * 3 + 1], x2 = x[n * 3 + 2];
    float v = fmaf(x0, W1[j], fmaf(x1, W1[64 + j], x2 * W1[128 + j]));
    h1[n * 64 + j] = v;
    float ps = v * as1[j];
    float pd = v * ad1[j];
    for (int o = 4; o >= 1; o >>= 1) {
        ps += __shfl_xor(ps, o, 8);
        pd += __shfl_xor(pd, o, 8);
    }
    if ((j & 7) == 0) {
        al_s[n * 8 + (j >> 3)] = ps;
        al_d[n * 8 + (j >> 3)] = pd;
    }
}

// fused layer-1 edge softmax + aggregation + bias + elu.  block = node, 64 threads.
__global__ void k_l1(const int* __restrict__ rowstart, const int* __restrict__ csr_src,
                     const float* __restrict__ al_s, const float* __restrict__ al_d,
                     const float* __restrict__ h1, const float* __restrict__ b1,
                     float* __restrict__ o1) {
    int n = blockIdx.x;
    int j = threadIdx.x;       // channel 0..63
    int h = j >> 3;            // head
    float ald = al_d[n * 8 + h];
    int start = rowstart[n], end = rowstart[n + 1];
    float m = -1e30f;
    for (int e = start; e < end; ++e) {
        int s = csr_src[e];
        m = fmaxf(m, lrelu(al_s[s * 8 + h] + ald));
    }
    float denom = 0.f, acc = 0.f;
    for (int e = start; e < end; ++e) {
        int s = csr_src[e];
        float ex = __expf(lrelu(al_s[s * 8 + h] + ald) - m);
        denom += ex;
        acc = fmaf(ex, h1[s * 64 + j], acc);
    }
    o1[n * 64 + j] = elu1(acc / denom + b1[j]);
}

// h2 = o1 @ W2, tiled 16 nodes/block so W2 is read 1250x not 20000x
__global__ void k5b_h2(const float* __restrict__ o1, const float* __restrict__ W2,
                       float* __restrict__ h2) {
    __shared__ float sO[16][64];
    int n0 = blockIdx.x * 16;
    int j = threadIdx.x;  // 512
    for (int i = j; i < 1024; i += 512) sO[i >> 6][i & 63] = o1[n0 * 64 + i];
    __syncthreads();
    float acc[16];
#pragma unroll
    for (int i = 0; i < 16; ++i) acc[i] = 0.f;
    for (int k = 0; k < 64; ++k) {
        float wv = W2[k * 512 + j];
#pragma unroll
        for (int i = 0; i < 16; ++i) acc[i] = fmaf(sO[i][k], wv, acc[i]);
    }
#pragma unroll
    for (int i = 0; i < 16; ++i) h2[(n0 + i) * 512 + j] = acc[i];
}

// al_s2/al_d2[n] = dot(h2[n], a2).  one wave per node, 4 waves/block.
__global__ void k5c_logits(const float* __restrict__ h2, const float* __restrict__ as2,
                           const float* __restrict__ ad2, float* __restrict__ al_s2,
                           float* __restrict__ al_d2) {
    int w = threadIdx.x >> 6, lane = threadIdx.x & 63;
    int n = blockIdx.x * 4 + w;
    const float4* hp = (const float4*)(h2 + n * 512 + lane * 8);
    const float4* sp = (const float4*)(as2 + lane * 8);
    const float4* dp = (const float4*)(ad2 + lane * 8);
    float4 h0 = hp[0], h1v = hp[1];
    float4 s0 = sp[0], s1 = sp[1];
    float4 d0 = dp[0], d1 = dp[1];
    float ps = h0.x * s0.x + h0.y * s0.y + h0.z * s0.z + h0.w * s0.w
             + h1v.x * s1.x + h1v.y * s1.y + h1v.z * s1.z + h1v.w * s1.w;
    float pd = h0.x * d0.x + h0.y * d0.y + h0.z * d0.z + h0.w * d0.w
             + h1v.x * d1.x + h1v.y * d1.y + h1v.z * d1.z + h1v.w * d1.w;
    for (int o = 32; o >= 1; o >>= 1) {
        ps += __shfl_xor(ps, o, 64);
        pd += __shfl_xor(pd, o, 64);
    }
    if (lane == 0) { al_s2[n] = ps; al_d2[n] = pd; }
}

// fused layer-2 softmax + aggregation + bias + elu + mean-pool scatter.
// block = node, 256 threads, 2 channels each (float2).
__global__ void k_l2(const int* __restrict__ rowstart, const int* __restrict__ csr_src,
                     const float* __restrict__ al_s2, const float* __restrict__ al_d2,
                     const float* __restrict__ h2, const float* __restrict__ b2,
                     const int* __restrict__ batch, float* __restrict__ sums) {
    int n = blockIdx.x;
    int t = threadIdx.x;  // owns channels 2t, 2t+1
    float ald = al_d2[n];
    int start = rowstart[n], end = rowstart[n + 1];
    float m = -1e30f;
    for (int e = start; e < end; ++e) {
        int s = csr_src[e];
        m = fmaxf(m, lrelu(al_s2[s] + ald));
    }
    float denom = 0.f;
    float2 acc = {0.f, 0.f};
    for (int e = start; e < end; ++e) {
        int s = csr_src[e];
        float ex = __expf(lrelu(al_s2[s] + ald) - m);
        denom += ex;
        float2 hv = ((const float2*)(h2 + s * 512))[t];
        acc.x = fmaf(ex, hv.x, acc.x);
        acc.y = fmaf(ex, hv.y, acc.y);
    }
    float inv = 1.f / denom;
    float v0 = elu1(acc.x * inv + b2[2 * t]);
    float v1 = elu1(acc.y * inv + b2[2 * t + 1]);
    int g = batch[n];
    atomicAdd(&sums[g * 512 + 2 * t], v0);
    atomicAdd(&sums[g * 512 + 2 * t + 1], v1);
}

// ---------- pooling + output ----------
__global__ void k9_cnt(const int* __restrict__ batch, float* __restrict__ cnt) {
    int t = blockIdx.x * blockDim.x + threadIdx.x;
    if (t >= NN) return;
    atomicAdd(&cnt[batch[t]], 1.0f);
}

__global__ void k10_final(const float* __restrict__ sums, const float* __restrict__ cnt,
                          const float* __restrict__ Wo, const float* __restrict__ bo,
                          float* __restrict__ out) {
    __shared__ float sp[512];
    int g = blockIdx.x, j = threadIdx.x;
    float c = cnt[g];
    c = c > 0.f ? c : 1.f;
    sp[j] = sums[g * 512 + j] / c;
    __syncthreads();
    float v = bo[j];
    for (int k = 0; k < 512; ++k) v = fmaf(sp[k], Wo[k * 512 + j], v);
    out[g * 512 + j] = v;
}

extern "C" void kernel_launch(void* const* d_in, const int* in_sizes, int n_in,
                              void* d_out, int out_size, void* d_ws, size_t ws_size,
                              hipStream_t stream) {
    const float* x     = (const float*)d_in[0];
    const int*   ei    = (const int*)d_in[1];    // [2, NE]
    const int*   batch = (const int*)d_in[2];    // [NN]
    const float* W1    = (const float*)d_in[3];
    const float* as1   = (const float*)d_in[4];
    const float* ad1   = (const float*)d_in[5];
    const float* b1    = (const float*)d_in[6];
    const float* W2    = (const float*)d_in[7];
    const float* as2   = (const float*)d_in[8];
    const float* ad2   = (const float*)d_in[9];
    const float* b2    = (const float*)d_in[10];
    const float* Wo    = (const float*)d_in[11];
    const float* bo    = (const float*)d_in[12];
    float* out = (float*)d_out;

    // ---- workspace arena (4-byte units) ----
    float* w = (float*)d_ws;
    float* h1    = w + 0;           // 1,280,000
    float* al_s1 = w + 1280000;     // 160,000
    float* al_d1 = w + 1440000;     // 160,000
    float* o1    = w + 1600000;     // 1,280,000
    float* h2    = w + 2880000;     // 10,240,000  (16B aligned: byte 11,520,000)
    float* al_s2 = w + 13120000;    // 20,000
    float* al_d2 = w + 13140000;    // 20,000
    int*   rowstart = (int*)(w + 13160000);  // 20,001
    int*   cursor   = (int*)(w + 13180008);  // 20,000
    int*   csr_src  = (int*)(w + 13200008);  // 340,000
    // ---- zero-initialized region ----
    int*   deg  = (int*)(w + 13540008);      // 20,000
    float* sums = w + 13560008;              // 32,768
    float* cnt  = w + 13592776;              // 64
    // zero region size: 52,832 units; total ws ~54.6 MB

    hipMemsetAsync(w + 13540008, 0, (size_t)52832 * 4, stream);

    k_hist   <<<(NT + 255) / 256, 256, 0, stream>>>(ei, deg);
    k_scan   <<<1, 1024, 0, stream>>>(deg, rowstart, cursor);
    k_scatter<<<(NT + 255) / 256, 256, 0, stream>>>(ei, cursor, csr_src);

    k1_h1    <<<NN, 64, 0, stream>>>(x, W1, as1, ad1, h1, al_s1, al_d1);
    k_l1     <<<NN, 64, 0, stream>>>(rowstart, csr_src, al_s1, al_d1, h1, b1, o1);
    k5b_h2   <<<NN / 16, 512, 0, stream>>>(o1, W2, h2);
    k5c_logits<<<NN / 4, 256, 0, stream>>>(h2, as2, ad2, al_s2, al_d2);
    k_l2     <<<NN, 256, 0, stream>>>(rowstart, csr_src, al_s2, al_d2, h2, b2, batch, sums);

    k9_cnt   <<<(NN + 255) / 256, 256, 0, stream>>>(batch, cnt);
    k10_final<<<NG, 512, 0, stream>>>(sums, cnt, Wo, bo, out);
}